// Round 2
// baseline (483.020 us; speedup 1.0000x reference)
//
#include <hip/hip_runtime.h>

#define NROWS 16384
#define DDIM  4096
#define NEXP  64
#define BM    64
#define DK    64
#define NTILES (DDIM / DK)   // 64
#define NBLK  (NROWS / BM)   // 256

// Fused: logits GEMM (fp64 accumulate, VALU) + noise + softmax + top-8 +
// per-block importance/load partial sums. fp64 ranking keys guarantee the
// same top-k order as the float64 numpy reference (min adjacent logit gap
// ~5e-7 >> fp64 accumulation error ~1e-13).
__global__ __launch_bounds__(256) void router_gemm_fused(
    const float* __restrict__ x, const float* __restrict__ Wg,
    const float* __restrict__ noise, float* __restrict__ out_gates,
    float* __restrict__ out_idx, float* __restrict__ ws_imp,
    float* __restrict__ ws_load)
{
    // 32 KB aliased: during GEMM = xT(16KB) + Wt(16KB); epilogue = fp64 logits
    __shared__ double smem[BM * NEXP];
    float* xT = (float*)smem;                 // [DK][BM]   tile of x^T, swizzled
    float* Wt = (float*)smem + DK * BM;       // [DK][NEXP] tile of W
    double (*logits64)[NEXP] = (double(*)[NEXP])smem;
    __shared__ float red[4][NEXP];

    const int tid  = threadIdx.x;
    const int lane = tid & 63;
    const int w    = tid >> 6;       // wave id 0..3
    const int rg   = tid >> 4;       // row-group 0..15 (4 rows each)
    const int cg   = tid & 15;       // col-group 0..15 (4 cols each)
    const int row0 = blockIdx.x * BM;

    // staging mapping: thread -> (row, col-chunk)
    const int srow = tid >> 2;                       // 0..63
    const int sc   = tid & 3;                        // 0..3
    const int sr   = srow ^ ((sc & 1) << 4);         // swizzled LDS row slot

    const float* xrow = x + (size_t)(row0 + srow) * DDIM;

    float4 px[4], pw[4];
    #pragma unroll
    for (int it = 0; it < 4; ++it) {                 // preload tile 0
        px[it] = *(const float4*)(xrow + (sc + 4 * it) * 4);
        const int f = tid + 256 * it;                // 0..1023 float4 slots of W tile
        pw[it] = *(const float4*)(Wg + (size_t)(f >> 4) * NEXP + (f & 15) * 4);
    }

    double acc[4][4];
    #pragma unroll
    for (int i = 0; i < 4; ++i)
        #pragma unroll
        for (int j = 0; j < 4; ++j) acc[i][j] = 0.0;

    for (int t = 0; t < NTILES; ++t) {
        __syncthreads();                             // compute of tile t-1 done
        #pragma unroll
        for (int it = 0; it < 4; ++it) {             // stage regs -> LDS
            const int f = tid + 256 * it;
            *(float4*)&Wt[(f >> 4) * NEXP + (f & 15) * 4] = pw[it];
            const int cfb = 4 * sc + 16 * it;        // k-index within tile
            xT[(cfb + 0) * BM + sr] = px[it].x;
            xT[(cfb + 1) * BM + sr] = px[it].y;
            xT[(cfb + 2) * BM + sr] = px[it].z;
            xT[(cfb + 3) * BM + sr] = px[it].w;
        }
        __syncthreads();
        if (t < NTILES - 1) {                        // prefetch tile t+1
            const float* xp = xrow + (t + 1) * DK;
            const float* wp = Wg + (size_t)(t + 1) * DK * NEXP;
            #pragma unroll
            for (int it = 0; it < 4; ++it) {
                px[it] = *(const float4*)(xp + (sc + 4 * it) * 4);
                const int f = tid + 256 * it;
                pw[it] = *(const float4*)(wp + (size_t)(f >> 4) * NEXP + (f & 15) * 4);
            }
        }
        #pragma unroll 4
        for (int k = 0; k < DK; ++k) {
            const int chunk = rg ^ (((k >> 2) & 1) << 2);   // undo write swizzle
            const float4 a = *(const float4*)&xT[k * BM + chunk * 4];
            const float4 b = *(const float4*)&Wt[k * NEXP + cg * 4];
            const double a0 = (double)a.x, a1 = (double)a.y,
                         a2 = (double)a.z, a3 = (double)a.w;
            const double b0 = (double)b.x, b1 = (double)b.y,
                         b2 = (double)b.z, b3 = (double)b.w;
            acc[0][0] = fma(a0, b0, acc[0][0]);
            acc[0][1] = fma(a0, b1, acc[0][1]);
            acc[0][2] = fma(a0, b2, acc[0][2]);
            acc[0][3] = fma(a0, b3, acc[0][3]);
            acc[1][0] = fma(a1, b0, acc[1][0]);
            acc[1][1] = fma(a1, b1, acc[1][1]);
            acc[1][2] = fma(a1, b2, acc[1][2]);
            acc[1][3] = fma(a1, b3, acc[1][3]);
            acc[2][0] = fma(a2, b0, acc[2][0]);
            acc[2][1] = fma(a2, b1, acc[2][1]);
            acc[2][2] = fma(a2, b2, acc[2][2]);
            acc[2][3] = fma(a2, b3, acc[2][3]);
            acc[3][0] = fma(a3, b0, acc[3][0]);
            acc[3][1] = fma(a3, b1, acc[3][1]);
            acc[3][2] = fma(a3, b2, acc[3][2]);
            acc[3][3] = fma(a3, b3, acc[3][3]);
        }
    }

    // ---- epilogue: fp64 logits -> LDS (aliased over dead x/W tiles) ----
    __syncthreads();
    #pragma unroll
    for (int i = 0; i < 4; ++i)
        #pragma unroll
        for (int j = 0; j < 4; ++j)
            logits64[rg * 4 + i][cg * 4 + j] = acc[i][j];
    __syncthreads();

    float impacc = 0.f, loadacc = 0.f;
    for (int rr = 0; rr < 16; ++rr) {
        const int row  = w * 16 + rr;
        const int grow = row0 + row;
        const double v64 = logits64[row][lane] +
                           (double)noise[(size_t)grow * NEXP + lane];

        double m = v64;
        #pragma unroll
        for (int off = 32; off; off >>= 1) m = fmax(m, __shfl_xor(m, off));
        const float ex = __expf((float)(v64 - m));
        float s = ex;
        #pragma unroll
        for (int off = 32; off; off >>= 1) s += __shfl_xor(s, off);
        const float g = ex * (1.0f / s);     // fp32 gate value (2% threshold)
        impacc += g;

        // top-8: repeated argmax butterfly keyed on fp64, carrying fp32 gate
        double work = v64;
        float myv = 0.f, sumtop = 0.f, bg;
        int myi = 0, mine = 0;
        #pragma unroll
        for (int j = 0; j < 8; ++j) {
            double bv = work; int bi = lane; bg = g;
            #pragma unroll
            for (int off = 32; off; off >>= 1) {
                const double ov = __shfl_xor(bv, off);
                const int    oi = __shfl_xor(bi, off);
                const float  og = __shfl_xor(bg, off);
                if (ov > bv || (ov == bv && oi < bi)) { bv = ov; bi = oi; bg = og; }
            }
            sumtop += bg;
            if (lane == j)  { myv = bg; myi = bi; }
            if (lane == bi) { work = -1e300; mine = 1; }
        }
        loadacc += (float)mine;

        if (lane < 8) {
            out_gates[(size_t)grow * 8 + lane] = myv / sumtop;
            out_idx  [(size_t)grow * 8 + lane] = (float)myi;
        }
    }

    // per-block partials (deterministic, no atomics)
    red[w][lane] = impacc;
    __syncthreads();
    if (w == 0) {
        ws_imp[(size_t)blockIdx.x * NEXP + lane] =
            red[0][lane] + red[1][lane] + red[2][lane] + red[3][lane];
    }
    __syncthreads();
    red[w][lane] = loadacc;
    __syncthreads();
    if (w == 0) {
        ws_load[(size_t)blockIdx.x * NEXP + lane] =
            red[0][lane] + red[1][lane] + red[2][lane] + red[3][lane];
    }
}

__global__ __launch_bounds__(256) void router_finalize(
    const float* __restrict__ ws_imp, const float* __restrict__ ws_load,
    float* __restrict__ loss_out)
{
    __shared__ float si[4][NEXP], sl[4][NEXP];
    const int tid = threadIdx.x;
    const int e = tid & 63;
    const int g = tid >> 6;           // 4 groups of 64 blocks
    float a = 0.f, b = 0.f;
    for (int blk = g * 64; blk < g * 64 + 64; ++blk) {
        a += ws_imp[blk * NEXP + e];
        b += ws_load[blk * NEXP + e];
    }
    si[g][e] = a; sl[g][e] = b;
    __syncthreads();
    if (tid < 64) {
        const float imp = (si[0][e] + si[1][e] + si[2][e] + si[3][e]) / (float)NROWS;
        const float ld  = (sl[0][e] + sl[1][e] + sl[2][e] + sl[3][e]) / (float)(NROWS * 8);
        float term = imp * ld;
        #pragma unroll
        for (int off = 32; off; off >>= 1) term += __shfl_xor(term, off);
        if (e == 0) *loss_out = term * (float)NEXP;
    }
}

extern "C" void kernel_launch(void* const* d_in, const int* in_sizes, int n_in,
                              void* d_out, int out_size, void* d_ws, size_t ws_size,
                              hipStream_t stream) {
    const float* x     = (const float*)d_in[0];
    const float* Wg    = (const float*)d_in[1];
    const float* noise = (const float*)d_in[2];
    float* out       = (float*)d_out;
    float* out_gates = out;                            // [16384*8]
    float* out_idx   = out + (size_t)NROWS * 8;        // [16384*8] as float
    float* loss_out  = out + (size_t)2 * NROWS * 8;    // [1]
    float* ws_imp  = (float*)d_ws;                     // [256*64]
    float* ws_load = ws_imp + NBLK * NEXP;             // [256*64]

    router_gemm_fused<<<NBLK, 256, 0, stream>>>(x, Wg, noise, out_gates, out_idx,
                                                ws_imp, ws_load);
    router_finalize<<<1, 256, 0, stream>>>(ws_imp, ws_load, loss_out);
}